// Round 1
// baseline (388.103 us; speedup 1.0000x reference)
//
#include <hip/hip_runtime.h>
#include <hip/hip_bf16.h>
#include <cstdint>
#include <cstddef>

using bf16 = __hip_bfloat16;
typedef __attribute__((ext_vector_type(8))) short short8;
typedef __attribute__((ext_vector_type(4))) float f32x4;

#define T_SEQ 2048
#define NHEAD 16
#define NKV 4
#define HD 128
#define CE 2048

__device__ __forceinline__ void gl_lds16(const void* g, void* l) {
  __builtin_amdgcn_global_load_lds(
      (const __attribute__((address_space(1))) unsigned int*)g,
      (__attribute__((address_space(3))) unsigned int*)l, 16, 0, 0);
}

// ---------------- elementwise f32 -> bf16 ----------------
__global__ void __launch_bounds__(256) cvt_bf16(const float* __restrict__ in,
                                                bf16* __restrict__ out, int n4) {
  const int i = blockIdx.x * blockDim.x + threadIdx.x;
  if (i >= n4) return;
  const float4 v = ((const float4*)in)[i];
  bf16 b0 = __float2bfloat16(v.x), b1 = __float2bfloat16(v.y),
       b2 = __float2bfloat16(v.z), b3 = __float2bfloat16(v.w);
  ushort4 u;
  u.x = *(const unsigned short*)&b0; u.y = *(const unsigned short*)&b1;
  u.z = *(const unsigned short*)&b2; u.w = *(const unsigned short*)&b3;
  ((ushort4*)out)[i] = u;
}

// ---------------- transpose + convert: Wt[n][k] = W[k][n], K rows = 2048 ----------------
__global__ void __launch_bounds__(256) transpose_cvt(const float* __restrict__ W,
                                                     bf16* __restrict__ Wt, int N) {
  __shared__ float tile[32][33];
  const int tx = threadIdx.x & 31, ty = threadIdx.x >> 5;  // 32 x 8
  const int bx = blockIdx.x, by = blockIdx.y;
#pragma unroll
  for (int i = 0; i < 4; i++) {
    const int r = by * 32 + ty + i * 8;
    tile[ty + i * 8][tx] = W[(size_t)r * N + bx * 32 + tx];
  }
  __syncthreads();
#pragma unroll
  for (int i = 0; i < 4; i++) {
    const int n = bx * 32 + ty + i * 8;
    Wt[(size_t)n * 2048 + by * 32 + tx] = __float2bfloat16(tile[tx][ty + i * 8]);
  }
}

// ---------------- GEMM: C(f32 MxN) = A(bf16 MxK,rm) @ Bt(bf16 NxK,rm)^T ----------------
// 128x128 tile, BK=64, 4 waves (2x2 of 64x64), global_load_lds staging with
// XOR-swizzled source (slot ^= row&7) so frag ds_read_b128 are conflict-minimal.
__global__ void __launch_bounds__(256) gemm_bt(const bf16* __restrict__ A,
                                               const bf16* __restrict__ Bt,
                                               float* __restrict__ C,
                                               int M, int N, int K) {
  __shared__ bf16 smA[128 * 64];
  __shared__ bf16 smB[128 * 64];
  const int tid = threadIdx.x, wid = tid >> 6, lane = tid & 63;
  const int l15 = lane & 15, l4 = lane >> 4;
  const int l8 = lane >> 3, l7 = lane & 7;
  const int row0 = blockIdx.y * 128, col0 = blockIdx.x * 128;
  const int wm = wid >> 1, wn = wid & 1;
  const int gcol = (l7 ^ l8) * 8;  // pre-swizzled source column (elements)

  f32x4 acc[4][4];
#pragma unroll
  for (int m = 0; m < 4; m++)
#pragma unroll
    for (int n = 0; n < 4; n++) acc[m][n] = (f32x4){0.f, 0.f, 0.f, 0.f};

  const bf16* Ab = A + (size_t)row0 * K + gcol;
  const bf16* Bb = Bt + (size_t)col0 * K + gcol;

  for (int k0 = 0; k0 < K; k0 += 64) {
    __syncthreads();  // previous compute done before overwrite
#pragma unroll
    for (int i = 0; i < 4; i++) {
      const int c = wid * 4 + i;           // 1KB chunk id (16 per operand)
      const int r = c * 8 + l8;            // tile row this lane stages
      gl_lds16(Ab + (size_t)r * K + k0, (void*)(smA + c * 512));
      gl_lds16(Bb + (size_t)r * K + k0, (void*)(smB + c * 512));
    }
    __syncthreads();  // drains vmcnt(0) -> staged data visible
#pragma unroll
    for (int kc = 0; kc < 2; kc++) {
      short8 af[4], bfr[4];
#pragma unroll
      for (int m = 0; m < 4; m++) {
        const int r = wm * 64 + m * 16 + l15;
        af[m] = *(const short8*)(smA + r * 64 + ((((kc << 2) | l4) ^ (r & 7)) * 8));
      }
#pragma unroll
      for (int n = 0; n < 4; n++) {
        const int r = wn * 64 + n * 16 + l15;
        bfr[n] = *(const short8*)(smB + r * 64 + ((((kc << 2) | l4) ^ (r & 7)) * 8));
      }
#pragma unroll
      for (int m = 0; m < 4; m++)
#pragma unroll
        for (int n = 0; n < 4; n++)
          acc[m][n] = __builtin_amdgcn_mfma_f32_16x16x32_bf16(af[m], bfr[n], acc[m][n], 0, 0, 0);
    }
  }
#pragma unroll
  for (int m = 0; m < 4; m++)
#pragma unroll
    for (int n = 0; n < 4; n++)
#pragma unroll
      for (int r = 0; r < 4; r++)
        C[(size_t)(row0 + wm * 64 + m * 16 + l4 * 4 + r) * N +
          (col0 + wn * 64 + n * 16 + l15)] = acc[m][n][r];
}

// ---------------- RMSNorm + RoPE + layout: one wave per (b,t,head-row) ----------------
// heads 0..15: q -> Q (B,H,T,D); 16..19: k -> K (B,KVH,T,D); 20..23: v -> Vt (B,KVH,D,T)
__global__ void __launch_bounds__(256) qkv_post(const float* __restrict__ QKV,
                                                const float* __restrict__ qw,
                                                const float* __restrict__ kw,
                                                bf16* __restrict__ Qo,
                                                bf16* __restrict__ Ko,
                                                bf16* __restrict__ Vto) {
  const int g = blockIdx.x * 4 + (threadIdx.x >> 6);
  const int lane = threadIdx.x & 63;
  const int hh = g % 24;
  const int bt = g / 24;
  const int b = bt >> 11, t = bt & (T_SEQ - 1);
  int off;
  if (hh < 16) off = hh * 128;
  else if (hh < 20) off = 2048 + (hh - 16) * 128;
  else off = 2560 + (hh - 20) * 128;
  const float2 x = *(const float2*)(QKV + (size_t)bt * 3072 + off + lane * 2);
  if (hh < 20) {
    float ss = x.x * x.x + x.y * x.y;
    ss += __shfl_xor(ss, 1);  ss += __shfl_xor(ss, 2);  ss += __shfl_xor(ss, 4);
    ss += __shfl_xor(ss, 8);  ss += __shfl_xor(ss, 16); ss += __shfl_xor(ss, 32);
    const float rms = rsqrtf(ss * (1.0f / 128.0f) + 1e-5f);
    const float* w = (hh < 16) ? qw : kw;
    const float x0 = x.x * rms * w[lane * 2];
    const float x1 = x.y * rms * w[lane * 2 + 1];
    // inv_freq = 10000^(-lane/64)
    const float inv = exp2f((float)lane * (-13.287712379549449f / 64.0f));
    const float th = (float)t * inv;
    const float sn = sinf(th), cs = cosf(th);
    const float y0 = x0 * cs - x1 * sn;
    const float y1 = x0 * sn + x1 * cs;
    const bf16 o0 = __float2bfloat16(y0), o1 = __float2bfloat16(y1);
    if (hh < 16) {
      bf16* d = Qo + ((size_t)(b * NHEAD + hh) * T_SEQ + t) * HD + lane * 2;
      d[0] = o0; d[1] = o1;
    } else {
      bf16* d = Ko + ((size_t)(b * NKV + (hh - 16)) * T_SEQ + t) * HD + lane * 2;
      d[0] = o0; d[1] = o1;
    }
  } else {
    bf16* d = Vto + ((size_t)(b * NKV + (hh - 20)) * HD + lane * 2) * T_SEQ + t;
    d[0] = __float2bfloat16(x.x);
    d[T_SEQ] = __float2bfloat16(x.y);
  }
}

// ---------------- GQA causal flash attention ----------------
// block = 4 waves, 64 q-rows (16/wave); KBLK=32; K + V^T staged in shared LDS
// (XOR-swizzled); online softmax with 16-lane shuffle reductions; P transposed
// through per-wave swizzled LDS; writes y bf16 rows (b*T+t, 2048).
__global__ void __launch_bounds__(256) attn_fwd(const bf16* __restrict__ Q,
                                                const bf16* __restrict__ K,
                                                const bf16* __restrict__ Vt,
                                                bf16* __restrict__ Y) {
  __shared__ bf16 smK[32 * 128];   // [key][kdim], slot(16B) ^= key&15
  __shared__ bf16 smV[128 * 32];   // [dim][key],  slot(16B) ^= (dim>>1)&3
  __shared__ bf16 smP[4][16 * 32]; // per-wave, slot(16B) ^= (row>>1)&3

  const int gb = blockIdx.x;
  const int qblk = gb & 31;        // T/64
  const int bh = gb >> 5;          // b*16+h
  const int h = bh & (NHEAD - 1);
  const int b = bh >> 4;
  const int bkv = b * NKV + (h >> 2);

  const int tid = threadIdx.x, wid = tid >> 6, lane = tid & 63;
  const int l15 = lane & 15, l4 = lane >> 4;
  const int q0 = qblk * 64 + wid * 16;

  const bf16* Qb = Q + (size_t)bh * T_SEQ * HD;
  const bf16* Kb = K + (size_t)bkv * T_SEQ * HD;
  const bf16* Vb = Vt + (size_t)bkv * HD * T_SEQ;

  short8 qa[4];
#pragma unroll
  for (int c = 0; c < 4; c++)
    qa[c] = *(const short8*)(Qb + (size_t)(q0 + l15) * HD + c * 32 + l4 * 8);

  f32x4 o[8];
#pragma unroll
  for (int n = 0; n < 8; n++) o[n] = (f32x4){0.f, 0.f, 0.f, 0.f};
  float mrow[4] = {-INFINITY, -INFINITY, -INFINITY, -INFINITY};
  float lrow[4] = {0.f, 0.f, 0.f, 0.f};

  const int ntiles = qblk * 2 + 2;
  const float scale = 0.08838834764831845f;  // 1/sqrt(128)

  for (int t = 0; t < ntiles; t++) {
    const int k0 = t * 32;
    __syncthreads();  // all waves done reading previous tile
#pragma unroll
    for (int i = 0; i < 2; i++) {
      const int c = wid * 2 + i;                 // 1KB chunks, 8 per operand
      const int kr = c * 4 + l4;                 // K tile row (key)
      const int gs = l15 ^ (kr & 15);
      gl_lds16(Kb + (size_t)(k0 + kr) * HD + gs * 8, (void*)(smK + c * 512));
      const int dr = c * 16 + (lane >> 2);       // V^T tile row (dim)
      const int gs2 = (lane & 3) ^ ((dr >> 1) & 3);
      gl_lds16(Vb + (size_t)dr * T_SEQ + k0 + gs2 * 8, (void*)(smV + c * 512));
    }
    __syncthreads();  // staging drained + visible

    if (k0 <= q0 + 15) {
      f32x4 s0 = {0.f, 0.f, 0.f, 0.f}, s1 = {0.f, 0.f, 0.f, 0.f};
#pragma unroll
      for (int kc = 0; kc < 4; kc++) {
        const int sl = ((kc << 2) | l4) ^ l15;
        short8 kb0 = *(const short8*)(smK + (size_t)l15 * 128 + sl * 8);
        short8 kb1 = *(const short8*)(smK + (size_t)(16 + l15) * 128 + sl * 8);
        s0 = __builtin_amdgcn_mfma_f32_16x16x32_bf16(qa[kc], kb0, s0, 0, 0, 0);
        s1 = __builtin_amdgcn_mfma_f32_16x16x32_bf16(qa[kc], kb1, s1, 0, 0, 0);
      }
      float sf[4], p0[4], p1[4];
#pragma unroll
      for (int r = 0; r < 4; r++) {
        const int qrow = q0 + l4 * 4 + r;
        float v0 = s0[r] * scale, v1 = s1[r] * scale;
        if (k0 + l15 > qrow) v0 = -INFINITY;
        if (k0 + 16 + l15 > qrow) v1 = -INFINITY;
        float mx = fmaxf(v0, v1);
        mx = fmaxf(mx, __shfl_xor(mx, 1));
        mx = fmaxf(mx, __shfl_xor(mx, 2));
        mx = fmaxf(mx, __shfl_xor(mx, 4));
        mx = fmaxf(mx, __shfl_xor(mx, 8));
        const float mnew = fmaxf(mrow[r], mx);
        const float e0 = __expf(v0 - mnew);
        const float e1 = __expf(v1 - mnew);
        float rs = e0 + e1;
        rs += __shfl_xor(rs, 1);
        rs += __shfl_xor(rs, 2);
        rs += __shfl_xor(rs, 4);
        rs += __shfl_xor(rs, 8);
        const float sc = __expf(mrow[r] - mnew);
        lrow[r] = lrow[r] * sc + rs;
        mrow[r] = mnew;
        sf[r] = sc;
        p0[r] = e0; p1[r] = e1;
      }
#pragma unroll
      for (int n = 0; n < 8; n++)
#pragma unroll
        for (int r = 0; r < 4; r++) o[n][r] *= sf[r];
      // transpose P (16x32) through per-wave swizzled LDS
#pragma unroll
      for (int r = 0; r < 4; r++) {
        const int row = l4 * 4 + r;
        const int rs2 = (row >> 1) & 3;
        const int sl0 = ((0 << 1) | (l15 >> 3)) ^ rs2;
        const int sl1 = ((1 << 1) | (l15 >> 3)) ^ rs2;
        smP[wid][row * 32 + sl0 * 8 + (l15 & 7)] = __float2bfloat16(p0[r]);
        smP[wid][row * 32 + sl1 * 8 + (l15 & 7)] = __float2bfloat16(p1[r]);
      }
      asm volatile("s_waitcnt lgkmcnt(0)" ::: "memory");
      __builtin_amdgcn_sched_barrier(0);
      short8 pa = *(const short8*)(&smP[wid][l15 * 32 + (l4 ^ ((l15 >> 1) & 3)) * 8]);
#pragma unroll
      for (int n = 0; n < 8; n++) {
        const int dim = n * 16 + l15;
        short8 vb = *(const short8*)(smV + (size_t)dim * 32 + (l4 ^ ((dim >> 1) & 3)) * 8);
        o[n] = __builtin_amdgcn_mfma_f32_16x16x32_bf16(pa, vb, o[n], 0, 0, 0);
      }
    }
  }
#pragma unroll
  for (int r = 0; r < 4; r++) {
    const float inv = 1.0f / lrow[r];
    const int qrow = q0 + l4 * 4 + r;
    bf16* yrow = Y + (size_t)(b * T_SEQ + qrow) * CE + h * HD;
#pragma unroll
    for (int n = 0; n < 8; n++)
      yrow[n * 16 + l15] = __float2bfloat16(o[n][r] * inv);
  }
}

// ---------------- launch ----------------
extern "C" void kernel_launch(void* const* d_in, const int* in_sizes, int n_in,
                              void* d_out, int out_size, void* d_ws, size_t ws_size,
                              hipStream_t stream) {
  const float* x   = (const float*)d_in[0];
  const float* wq  = (const float*)d_in[1];
  const float* wk  = (const float*)d_in[2];
  const float* wv  = (const float*)d_in[3];
  const float* wc  = (const float*)d_in[4];
  const float* qnw = (const float*)d_in[5];
  const float* knw = (const float*)d_in[6];
  float* out = (float*)d_out;

  char* ws = (char*)d_ws;
  bf16*  xb    = (bf16*)(ws);                    // 16 MB: x as bf16 (4096x2048)
  bf16*  wqkvt = (bf16*)(ws + 16777216);         // 12 MB: [wq|wk|wv]^T (3072x2048)
  bf16*  wct   = (bf16*)(ws + 29360128);         //  8 MB: wc^T (2048x2048)
  float* qkv   = (float*)(ws + 37748736);        // 48 MB: QKV f32 (4096x3072)
  bf16*  Qb    = (bf16*)(ws + 88080384);         // 16 MB: Q (B,H,T,D)
  bf16*  Kb    = (bf16*)(ws + 104857600);        //  4 MB: K (B,KVH,T,D)
  bf16*  Vtb   = (bf16*)(ws + 109051904);        //  4 MB: V^T (B,KVH,D,T)
  bf16*  yb    = (bf16*)(ws + 113246208);        // 16 MB: attn out (4096x2048)

  cvt_bf16<<<8192, 256, 0, stream>>>(x, xb, 2097152);
  transpose_cvt<<<dim3(64, 64), 256, 0, stream>>>(wq, wqkvt, 2048);
  transpose_cvt<<<dim3(16, 64), 256, 0, stream>>>(wk, wqkvt + (size_t)2048 * 2048, 512);
  transpose_cvt<<<dim3(16, 64), 256, 0, stream>>>(wv, wqkvt + (size_t)2560 * 2048, 512);
  transpose_cvt<<<dim3(64, 64), 256, 0, stream>>>(wc, wct, 2048);
  gemm_bt<<<dim3(24, 32), 256, 0, stream>>>(xb, wqkvt, qkv, 4096, 3072, 2048);
  qkv_post<<<24576, 256, 0, stream>>>(qkv, qnw, knw, Qb, Kb, Vtb);
  attn_fwd<<<1024, 256, 0, stream>>>(Qb, Kb, Vtb, yb);
  gemm_bt<<<dim3(16, 32), 256, 0, stream>>>(yb, wct, out, 4096, 2048, 2048);
}

// Round 2
// 241.079 us; speedup vs baseline: 1.6099x; 1.6099x over previous
//
#include <hip/hip_runtime.h>
#include <hip/hip_bf16.h>
#include <cstdint>
#include <cstddef>

using bf16 = __hip_bfloat16;
typedef __attribute__((ext_vector_type(8))) short short8;
typedef __attribute__((ext_vector_type(4))) float f32x4;
typedef __attribute__((ext_vector_type(16))) float f32x16;

#define T_SEQ 2048
#define NHEAD 16
#define NKV 4
#define HD 128
#define CE 2048

__device__ __forceinline__ void gl_lds16(const void* g, void* l) {
  __builtin_amdgcn_global_load_lds(
      (const __attribute__((address_space(1))) unsigned int*)g,
      (__attribute__((address_space(3))) unsigned int*)l, 16, 0, 0);
}

__device__ __forceinline__ unsigned int cvtpk_bf16(float lo, float hi) {
  unsigned int r;
  asm("v_cvt_pk_bf16_f32 %0, %1, %2" : "=v"(r) : "v"(lo), "v"(hi));
  return r;
}

// swap upper 32 lanes of x with lower 32 lanes of y (both results used)
__device__ __forceinline__ void plswap(unsigned int& x, unsigned int& y, int hi) {
#if __has_builtin(__builtin_amdgcn_permlane32_swap)
  auto r = __builtin_amdgcn_permlane32_swap(x, y, false, false);
  x = r[0];
  y = r[1];
#else
  unsigned int xp = (unsigned int)__shfl_xor((int)x, 32);
  unsigned int yp = (unsigned int)__shfl_xor((int)y, 32);
  unsigned int nx = hi ? yp : x;
  unsigned int ny = hi ? y : xp;
  x = nx;
  y = ny;
#endif
}

// ---------------- elementwise f32 -> bf16 ----------------
__global__ void __launch_bounds__(256) cvt_bf16(const float* __restrict__ in,
                                                bf16* __restrict__ out, int n4) {
  const int i = blockIdx.x * blockDim.x + threadIdx.x;
  if (i >= n4) return;
  const float4 v = ((const float4*)in)[i];
  bf16 b0 = __float2bfloat16(v.x), b1 = __float2bfloat16(v.y),
       b2 = __float2bfloat16(v.z), b3 = __float2bfloat16(v.w);
  ushort4 u;
  u.x = *(const unsigned short*)&b0; u.y = *(const unsigned short*)&b1;
  u.z = *(const unsigned short*)&b2; u.w = *(const unsigned short*)&b3;
  ((ushort4*)out)[i] = u;
}

// ---------------- transpose + convert: Wt[n][k] = W[k][n], K rows = 2048 ----------------
__global__ void __launch_bounds__(256) transpose_cvt(const float* __restrict__ W,
                                                     bf16* __restrict__ Wt, int N) {
  __shared__ float tile[32][33];
  const int tx = threadIdx.x & 31, ty = threadIdx.x >> 5;  // 32 x 8
  const int bx = blockIdx.x, by = blockIdx.y;
#pragma unroll
  for (int i = 0; i < 4; i++) {
    const int r = by * 32 + ty + i * 8;
    tile[ty + i * 8][tx] = W[(size_t)r * N + bx * 32 + tx];
  }
  __syncthreads();
#pragma unroll
  for (int i = 0; i < 4; i++) {
    const int n = bx * 32 + ty + i * 8;
    Wt[(size_t)n * 2048 + by * 32 + tx] = __float2bfloat16(tile[tx][ty + i * 8]);
  }
}

// ---------------- GEMM: C(f32 MxN) = A(bf16 MxK,rm) @ Bt(bf16 NxK,rm)^T ----------------
__global__ void __launch_bounds__(256) gemm_bt(const bf16* __restrict__ A,
                                               const bf16* __restrict__ Bt,
                                               float* __restrict__ C,
                                               int M, int N, int K) {
  __shared__ bf16 smA[128 * 64];
  __shared__ bf16 smB[128 * 64];
  const int tid = threadIdx.x, wid = tid >> 6, lane = tid & 63;
  const int l15 = lane & 15, l4 = lane >> 4;
  const int l8 = lane >> 3, l7 = lane & 7;
  const int row0 = blockIdx.y * 128, col0 = blockIdx.x * 128;
  const int wm = wid >> 1, wn = wid & 1;
  const int gcol = (l7 ^ l8) * 8;  // pre-swizzled source column (elements)

  f32x4 acc[4][4];
#pragma unroll
  for (int m = 0; m < 4; m++)
#pragma unroll
    for (int n = 0; n < 4; n++) acc[m][n] = (f32x4){0.f, 0.f, 0.f, 0.f};

  const bf16* Ab = A + (size_t)row0 * K + gcol;
  const bf16* Bb = Bt + (size_t)col0 * K + gcol;

  for (int k0 = 0; k0 < K; k0 += 64) {
    __syncthreads();
#pragma unroll
    for (int i = 0; i < 4; i++) {
      const int c = wid * 4 + i;
      const int r = c * 8 + l8;
      gl_lds16(Ab + (size_t)r * K + k0, (void*)(smA + c * 512));
      gl_lds16(Bb + (size_t)r * K + k0, (void*)(smB + c * 512));
    }
    __syncthreads();
#pragma unroll
    for (int kc = 0; kc < 2; kc++) {
      short8 af[4], bfr[4];
#pragma unroll
      for (int m = 0; m < 4; m++) {
        const int r = wm * 64 + m * 16 + l15;
        af[m] = *(const short8*)(smA + r * 64 + ((((kc << 2) | l4) ^ (r & 7)) * 8));
      }
#pragma unroll
      for (int n = 0; n < 4; n++) {
        const int r = wn * 64 + n * 16 + l15;
        bfr[n] = *(const short8*)(smB + r * 64 + ((((kc << 2) | l4) ^ (r & 7)) * 8));
      }
#pragma unroll
      for (int m = 0; m < 4; m++)
#pragma unroll
        for (int n = 0; n < 4; n++)
          acc[m][n] = __builtin_amdgcn_mfma_f32_16x16x32_bf16(af[m], bfr[n], acc[m][n], 0, 0, 0);
    }
  }
#pragma unroll
  for (int m = 0; m < 4; m++)
#pragma unroll
    for (int n = 0; n < 4; n++)
#pragma unroll
      for (int r = 0; r < 4; r++)
        C[(size_t)(row0 + wm * 64 + m * 16 + l4 * 4 + r) * N +
          (col0 + wn * 64 + n * 16 + l15)] = acc[m][n][r];
}

// ---------------- RMSNorm + RoPE + layout ----------------
__global__ void __launch_bounds__(256) qkv_post(const float* __restrict__ QKV,
                                                const float* __restrict__ qw,
                                                const float* __restrict__ kw,
                                                bf16* __restrict__ Qo,
                                                bf16* __restrict__ Ko,
                                                bf16* __restrict__ Vto) {
  const int g = blockIdx.x * 4 + (threadIdx.x >> 6);
  const int lane = threadIdx.x & 63;
  const int hh = g % 24;
  const int bt = g / 24;
  const int b = bt >> 11, t = bt & (T_SEQ - 1);
  int off;
  if (hh < 16) off = hh * 128;
  else if (hh < 20) off = 2048 + (hh - 16) * 128;
  else off = 2560 + (hh - 20) * 128;
  const float2 x = *(const float2*)(QKV + (size_t)bt * 3072 + off + lane * 2);
  if (hh < 20) {
    float ss = x.x * x.x + x.y * x.y;
    ss += __shfl_xor(ss, 1);  ss += __shfl_xor(ss, 2);  ss += __shfl_xor(ss, 4);
    ss += __shfl_xor(ss, 8);  ss += __shfl_xor(ss, 16); ss += __shfl_xor(ss, 32);
    const float rms = rsqrtf(ss * (1.0f / 128.0f) + 1e-5f);
    const float* w = (hh < 16) ? qw : kw;
    const float x0 = x.x * rms * w[lane * 2];
    const float x1 = x.y * rms * w[lane * 2 + 1];
    const float inv = exp2f((float)lane * (-13.287712379549449f / 64.0f));
    const float th = (float)t * inv;
    const float sn = sinf(th), cs = cosf(th);
    const float y0 = x0 * cs - x1 * sn;
    const float y1 = x0 * sn + x1 * cs;
    const bf16 o0 = __float2bfloat16(y0), o1 = __float2bfloat16(y1);
    if (hh < 16) {
      bf16* d = Qo + ((size_t)(b * NHEAD + hh) * T_SEQ + t) * HD + lane * 2;
      d[0] = o0; d[1] = o1;
    } else {
      bf16* d = Ko + ((size_t)(b * NKV + (hh - 16)) * T_SEQ + t) * HD + lane * 2;
      d[0] = o0; d[1] = o1;
    }
  } else {
    bf16* d = Vto + ((size_t)(b * NKV + (hh - 20)) * HD + lane * 2) * T_SEQ + t;
    d[0] = __float2bfloat16(x.x);
    d[T_SEQ] = __float2bfloat16(x.y);
  }
}

// ---------------- GQA causal flash attention, swapped-operand 32x32 MFMA ----------------
// 4 waves x 32 q-rows = 128-row q-tile; KVBLK=128 (4 key-groups of 32).
// QK^T as mfma(K, Q^T) -> lane holds S[key][q=lane&31]; PV as mfma(V^T, P) ->
// O^T accum with q lane-local. Softmax fully lane-local (one shfl_xor(32)/tile).
// K LDS [128kv][128d], V^T LDS [128d][128kv]; 256B rows, slot ^= row&15 swizzle.
__global__ void __launch_bounds__(256, 2) attn_fwd(const bf16* __restrict__ Q,
                                                   const bf16* __restrict__ K,
                                                   const bf16* __restrict__ Vt,
                                                   bf16* __restrict__ Y) {
  __shared__ bf16 smK[128 * 128];
  __shared__ bf16 smV[128 * 128];

  const int bid = blockIdx.x;
  const int p = bid & 255, sdx = bid >> 8;
  const int bh = p & 31;            // b*16 + h
  const int jh = p >> 5;            // 0..7
  const int jq = sdx ? (15 - jh) : jh;  // complementary pairing for balance
  const int h = bh & (NHEAD - 1), b = bh >> 4;
  const int bkv = b * NKV + (h >> 2);

  const int tid = threadIdx.x, wid = tid >> 6, lane = tid & 63;
  const int l31 = lane & 31, hi = lane >> 5;
  const int bq0 = jq * 128;
  const int q0w = bq0 + wid * 32;

  const bf16* Kb = K + (size_t)bkv * T_SEQ * HD;
  const bf16* Vb = Vt + (size_t)bkv * HD * T_SEQ;

  // Q fragments: lane holds Q[q0w + l31][dstep*16 + hi*8 .. +7]
  const bf16* Qrow = Q + ((size_t)bh * T_SEQ + q0w + l31) * HD + hi * 8;
  short8 qf[8];
#pragma unroll
  for (int ds = 0; ds < 8; ds++) qf[ds] = *(const short8*)(Qrow + ds * 16);

  f32x16 o[4];
#pragma unroll
  for (int d = 0; d < 4; d++) o[d] = (f32x16)(0.f);
  float mrun = -INFINITY, lrun = 0.f;

  constexpr float CL = 0.08838834764831845f * 1.44269504088896340736f;
  const int trow = tid >> 4, tslot = tid & 15;  // staging coords

  for (int t = 0; t <= jq; t++) {
    const int k0 = t * 128;
    __syncthreads();  // previous tile's reads done
#pragma unroll
    for (int i = 0; i < 8; i++) {
      const int row = i * 16 + trow;
      const int ss = (tslot ^ (row & 15)) * 8;
      gl_lds16(Kb + (size_t)(k0 + row) * HD + ss, (void*)((char*)smK + i * 4096 + wid * 1024));
      gl_lds16(Vb + (size_t)row * T_SEQ + k0 + ss, (void*)((char*)smV + i * 4096 + wid * 1024));
    }
    __syncthreads();  // staging drained (vmcnt 0 before barrier)

    const bool lastt = (t == jq);
    const int glim = lastt ? wid : 3;

    f32x16 sg[4];
    // ---- QK^T: sg[g] = K[g] . Q^T  (lane: q = l31, 16 key-rows via regs) ----
#pragma unroll
    for (int g = 0; g < 4; g++) {
      if (g > glim) continue;
      f32x16 acc = (f32x16)(0.f);
#pragma unroll
      for (int ds = 0; ds < 8; ds++) {
        const int row = g * 32 + l31;
        const short8 kf = *(const short8*)(smK + (size_t)row * 128 +
                                           (((ds << 1) | hi) ^ (row & 15)) * 8);
        acc = __builtin_amdgcn_mfma_f32_32x32x16_bf16(kf, qf[ds], acc, 0, 0, 0);
      }
      sg[g] = acc;
    }
    // ---- mask diagonal group + tile max (lane-local) ----
    float tmax = -INFINITY;
#pragma unroll
    for (int g = 0; g < 4; g++) {
      if (g > glim) continue;
      if (lastt && g == wid) {
#pragma unroll
        for (int r = 0; r < 16; r++) {
          const int kr = (r & 3) + 8 * (r >> 2) + (hi << 2);
          if (kr > l31) sg[g][r] = -INFINITY;
        }
      }
#pragma unroll
      for (int r = 0; r < 16; r++) tmax = fmaxf(tmax, sg[g][r]);
    }
    tmax = fmaxf(tmax, __shfl_xor(tmax, 32));
    const float mnew = fmaxf(mrun, tmax);
    const float f = exp2f((mrun - mnew) * CL);
    mrun = mnew;
    lrun *= f;
#pragma unroll
    for (int d = 0; d < 4; d++)
#pragma unroll
      for (int r = 0; r < 16; r++) o[d][r] *= f;

    // ---- per group: exp, P-frag build (cvt_pk + permlane32_swap), PV ----
    float lsum = 0.f;
#pragma unroll
    for (int g = 0; g < 4; g++) {
      if (g > glim) continue;
      float pp[16];
      float s0 = 0.f, s1 = 0.f;
#pragma unroll
      for (int r = 0; r < 16; r++) pp[r] = exp2f((sg[g][r] - mnew) * CL);
#pragma unroll
      for (int r = 0; r < 8; r++) { s0 += pp[2 * r]; s1 += pp[2 * r + 1]; }
      lsum += s0 + s1;

      unsigned int w0 = cvtpk_bf16(pp[0], pp[1]),  w2 = cvtpk_bf16(pp[4], pp[5]);
      unsigned int w1 = cvtpk_bf16(pp[2], pp[3]),  w3 = cvtpk_bf16(pp[6], pp[7]);
      unsigned int w4 = cvtpk_bf16(pp[8], pp[9]),  w6 = cvtpk_bf16(pp[12], pp[13]);
      unsigned int w5 = cvtpk_bf16(pp[10], pp[11]), w7 = cvtpk_bf16(pp[14], pp[15]);
      plswap(w0, w2, hi); plswap(w1, w3, hi);
      plswap(w4, w6, hi); plswap(w5, w7, hi);
      union { unsigned int u[4]; short8 s8; } pa0, pa1;
      pa0.u[0] = w0; pa0.u[1] = w1; pa0.u[2] = w2; pa0.u[3] = w3;  // keys g*32 + 0..15
      pa1.u[0] = w4; pa1.u[1] = w5; pa1.u[2] = w6; pa1.u[3] = w7;  // keys g*32 + 16..31

#pragma unroll
      for (int d = 0; d < 4; d++) {
        const int row = d * 32 + l31;
        const int ks0 = g * 2, ks1 = g * 2 + 1;
        const short8 vf0 = *(const short8*)(smV + (size_t)row * 128 +
                                            (((ks0 << 1) | hi) ^ (row & 15)) * 8);
        const short8 vf1 = *(const short8*)(smV + (size_t)row * 128 +
                                            (((ks1 << 1) | hi) ^ (row & 15)) * 8);
        o[d] = __builtin_amdgcn_mfma_f32_32x32x16_bf16(vf0, pa0.s8, o[d], 0, 0, 0);
        o[d] = __builtin_amdgcn_mfma_f32_32x32x16_bf16(vf1, pa1.s8, o[d], 0, 0, 0);
      }
    }
    lrun += lsum + __shfl_xor(lsum, 32);
  }

  // ---- epilogue: O^T regs -> Y[b*T + q][h*128 + d], q = q0w + l31 ----
  const float inv = 1.0f / lrun;
  bf16* yrow = Y + ((size_t)(b * T_SEQ + q0w + l31)) * CE + h * HD;
#pragma unroll
  for (int d = 0; d < 4; d++) {
#pragma unroll
    for (int rg = 0; rg < 4; rg++) {
      ushort4 u;
      bf16 e0 = __float2bfloat16(o[d][rg * 4 + 0] * inv);
      bf16 e1 = __float2bfloat16(o[d][rg * 4 + 1] * inv);
      bf16 e2 = __float2bfloat16(o[d][rg * 4 + 2] * inv);
      bf16 e3 = __float2bfloat16(o[d][rg * 4 + 3] * inv);
      u.x = *(const unsigned short*)&e0; u.y = *(const unsigned short*)&e1;
      u.z = *(const unsigned short*)&e2; u.w = *(const unsigned short*)&e3;
      *(ushort4*)(yrow + d * 32 + rg * 8 + (hi << 2)) = u;
    }
  }
}

// ---------------- launch ----------------
extern "C" void kernel_launch(void* const* d_in, const int* in_sizes, int n_in,
                              void* d_out, int out_size, void* d_ws, size_t ws_size,
                              hipStream_t stream) {
  const float* x   = (const float*)d_in[0];
  const float* wq  = (const float*)d_in[1];
  const float* wk  = (const float*)d_in[2];
  const float* wv  = (const float*)d_in[3];
  const float* wc  = (const float*)d_in[4];
  const float* qnw = (const float*)d_in[5];
  const float* knw = (const float*)d_in[6];
  float* out = (float*)d_out;

  char* ws = (char*)d_ws;
  bf16*  xb    = (bf16*)(ws);                    // 16 MB
  bf16*  wqkvt = (bf16*)(ws + 16777216);         // 12 MB
  bf16*  wct   = (bf16*)(ws + 29360128);         //  8 MB
  float* qkv   = (float*)(ws + 37748736);        // 48 MB
  bf16*  Qb    = (bf16*)(ws + 88080384);         // 16 MB (B,H,T,D)
  bf16*  Kb    = (bf16*)(ws + 104857600);        //  4 MB (B,KVH,T,D)
  bf16*  Vtb   = (bf16*)(ws + 109051904);        //  4 MB (B,KVH,D,T)
  bf16*  yb    = (bf16*)(ws + 113246208);        // 16 MB

  cvt_bf16<<<8192, 256, 0, stream>>>(x, xb, 2097152);
  transpose_cvt<<<dim3(64, 64), 256, 0, stream>>>(wq, wqkvt, 2048);
  transpose_cvt<<<dim3(16, 64), 256, 0, stream>>>(wk, wqkvt + (size_t)2048 * 2048, 512);
  transpose_cvt<<<dim3(16, 64), 256, 0, stream>>>(wv, wqkvt + (size_t)2560 * 2048, 512);
  transpose_cvt<<<dim3(64, 64), 256, 0, stream>>>(wc, wct, 2048);
  gemm_bt<<<dim3(24, 32), 256, 0, stream>>>(xb, wqkvt, qkv, 4096, 3072, 2048);
  qkv_post<<<24576, 256, 0, stream>>>(qkv, qnw, knw, Qb, Kb, Vtb);
  attn_fwd<<<512, 256, 0, stream>>>(Qb, Kb, Vtb, yb);
  gemm_bt<<<dim3(16, 32), 256, 0, stream>>>(yb, wct, out, 4096, 2048, 2048);
}

// Round 3
// 240.564 us; speedup vs baseline: 1.6133x; 1.0021x over previous
//
#include <hip/hip_runtime.h>
#include <hip/hip_bf16.h>
#include <cstdint>
#include <cstddef>

using bf16 = __hip_bfloat16;
typedef __attribute__((ext_vector_type(8))) short short8;
typedef __attribute__((ext_vector_type(4))) float f32x4;
typedef __attribute__((ext_vector_type(16))) float f32x16;

#define T_SEQ 2048
#define NHEAD 16
#define NKV 4
#define HD 128
#define CE 2048

__device__ __forceinline__ void gl_lds16(const void* g, void* l) {
  __builtin_amdgcn_global_load_lds(
      (const __attribute__((address_space(1))) unsigned int*)g,
      (__attribute__((address_space(3))) unsigned int*)l, 16, 0, 0);
}

__device__ __forceinline__ unsigned int cvtpk_bf16(float lo, float hi) {
  unsigned int r;
  asm("v_cvt_pk_bf16_f32 %0, %1, %2" : "=v"(r) : "v"(lo), "v"(hi));
  return r;
}

__device__ __forceinline__ void plswap(unsigned int& x, unsigned int& y, int hi) {
#if __has_builtin(__builtin_amdgcn_permlane32_swap)
  auto r = __builtin_amdgcn_permlane32_swap(x, y, false, false);
  x = r[0];
  y = r[1];
#else
  unsigned int xp = (unsigned int)__shfl_xor((int)x, 32);
  unsigned int yp = (unsigned int)__shfl_xor((int)y, 32);
  unsigned int nx = hi ? yp : x;
  unsigned int ny = hi ? y : xp;
  x = nx;
  y = ny;
#endif
}

// ---------------- elementwise f32 -> bf16 ----------------
__global__ void __launch_bounds__(256) cvt_bf16(const float* __restrict__ in,
                                                bf16* __restrict__ out, int n4) {
  const int i = blockIdx.x * blockDim.x + threadIdx.x;
  if (i >= n4) return;
  const float4 v = ((const float4*)in)[i];
  bf16 b0 = __float2bfloat16(v.x), b1 = __float2bfloat16(v.y),
       b2 = __float2bfloat16(v.z), b3 = __float2bfloat16(v.w);
  ushort4 u;
  u.x = *(const unsigned short*)&b0; u.y = *(const unsigned short*)&b1;
  u.z = *(const unsigned short*)&b2; u.w = *(const unsigned short*)&b3;
  ((ushort4*)out)[i] = u;
}

// ---------------- transpose + convert: Wt[n][k] = W[k][n], K rows = 2048 ----------------
__global__ void __launch_bounds__(256) transpose_cvt(const float* __restrict__ W,
                                                     bf16* __restrict__ Wt, int N) {
  __shared__ float tile[32][33];
  const int tx = threadIdx.x & 31, ty = threadIdx.x >> 5;  // 32 x 8
  const int bx = blockIdx.x, by = blockIdx.y;
#pragma unroll
  for (int i = 0; i < 4; i++) {
    const int r = by * 32 + ty + i * 8;
    tile[ty + i * 8][tx] = W[(size_t)r * N + bx * 32 + tx];
  }
  __syncthreads();
#pragma unroll
  for (int i = 0; i < 4; i++) {
    const int n = bx * 32 + ty + i * 8;
    Wt[(size_t)n * 2048 + by * 32 + tx] = __float2bfloat16(tile[tx][ty + i * 8]);
  }
}

// ---------------- 8-phase 256-class GEMM: C(f32) = A(bf16 MxK) @ Bt(bf16 NxK)^T ----------
// 512 thr / 8 waves (WM x WN), BK=64, double-buffered LDS, 4 phases per K-tile.
// Counted vmcnt (never 0 in loop): B(t+1) staged at P1, A(t+2) at P4, vmcnt(AL)
// before P4's trailing barrier guarantees next tile's data landed for all waves.
#define LOADA(mh)                                                              \
  _Pragma("unroll") for (int i = 0; i < MF / 2; i++) {                         \
    const int lrow = wr * (BM / WM) + ((mh) * (MF / 2) + i) * 16 + l15;        \
    _Pragma("unroll") for (int kk = 0; kk < 2; kk++) {                         \
      areg[i][kk] = *(const short8*)(sA + lrow * 64 +                          \
                    ((((kk << 2) | l4) ^ (lrow & 7)) << 3));                   \
    }                                                                          \
  }

#define LOADB(nh)                                                              \
  _Pragma("unroll") for (int j = 0; j < NF / 2; j++) {                         \
    const int lrow = wc * (BN / WN) + ((nh) * (NF / 2) + j) * 16 + l15;        \
    _Pragma("unroll") for (int kk = 0; kk < 2; kk++) {                         \
      breg[j][kk] = *(const short8*)(sB + lrow * 64 +                          \
                    ((((kk << 2) | l4) ^ (lrow & 7)) << 3));                   \
    }                                                                          \
  }

#define MFMAQ(mh, nh)                                                          \
  __builtin_amdgcn_s_setprio(1);                                               \
  _Pragma("unroll") for (int i = 0; i < MF / 2; i++)                           \
  _Pragma("unroll") for (int j = 0; j < NF / 2; j++)                           \
  _Pragma("unroll") for (int kk = 0; kk < 2; kk++)                             \
    acc[(mh) * (MF / 2) + i][(nh) * (NF / 2) + j] =                            \
        __builtin_amdgcn_mfma_f32_16x16x32_bf16(                               \
            areg[i][kk], breg[j][kk],                                          \
            acc[(mh) * (MF / 2) + i][(nh) * (NF / 2) + j], 0, 0, 0);           \
  __builtin_amdgcn_s_setprio(0);

template <int BM, int BN, int WM, int WN>
__global__ void __launch_bounds__(512, 2)
gemm8p(const bf16* __restrict__ A, const bf16* __restrict__ Bt,
       float* __restrict__ C, int M, int N, int K) {
  constexpr int MF = BM / WM / 16;
  constexpr int NF = BN / WN / 16;
  constexpr int AL = BM / 64;  // A stage loads per thread
  constexpr int BL = BN / 64;
  __shared__ bf16 smA[2][BM * 64];
  __shared__ bf16 smB[2][BN * 64];

  const int tid = threadIdx.x, lane = tid & 63, wid = tid >> 6;
  const int l15 = lane & 15, l4 = lane >> 4;
  const int wr = wid / WN, wc = wid % WN;

  // bijective XCD-aware block swizzle (m204 variant)
  const int nwg = gridDim.x;
  const int q = nwg >> 3, r = nwg & 7;
  const int xcd = blockIdx.x & 7, lin = blockIdx.x >> 3;
  const int wg = (xcd < r ? xcd * (q + 1) : r * (q + 1) + (xcd - r) * q) + lin;
  const int gw = N / BN;
  const int by = wg / gw, bx = wg % gw;
  const int row0 = by * BM, col0 = bx * BN;
  const int NT = K >> 6;

  const bf16* Ag = A + (size_t)row0 * K;
  const bf16* Bg = Bt + (size_t)col0 * K;

  auto stageA = [&](int t, int pbuf) {
    const int k0 = t << 6;
#pragma unroll
    for (int j = 0; j < AL; j++) {
      const int c = j * 512 + tid;
      const int rowi = c >> 3;
      gl_lds16(Ag + (size_t)rowi * K + k0 + (((c & 7) ^ (rowi & 7)) << 3),
               (void*)(&smA[pbuf][c << 3]));
    }
  };
  auto stageB = [&](int t, int pbuf) {
    const int k0 = t << 6;
#pragma unroll
    for (int j = 0; j < BL; j++) {
      const int c = j * 512 + tid;
      const int rowi = c >> 3;
      gl_lds16(Bg + (size_t)rowi * K + k0 + (((c & 7) ^ (rowi & 7)) << 3),
               (void*)(&smB[pbuf][c << 3]));
    }
  };

  f32x4 acc[MF][NF];
#pragma unroll
  for (int i = 0; i < MF; i++)
#pragma unroll
    for (int j = 0; j < NF; j++) acc[i][j] = (f32x4){0.f, 0.f, 0.f, 0.f};
  short8 areg[MF / 2][2], breg[NF / 2][2];

  // prologue: A(0), B(0) must land; A(1) may stay in flight
  stageA(0, 0);
  stageB(0, 0);
  stageA(1, 1);
  asm volatile("s_waitcnt vmcnt(%0)" ::"i"(AL) : "memory");
  __builtin_amdgcn_s_barrier();

  for (int t = 0; t < NT; ++t) {
    const int buf = t & 1;
    const bf16* sA = smA[buf];
    const bf16* sB = smB[buf];
    const int tB = (t + 1 < NT) ? t + 1 : NT - 1;  // clamped (redundant at tail)
    const int tA = (t + 2 < NT) ? t + 2 : NT - 1;

    // ---- P1: stage B(t+1) -> other buf; compute quadrant (0,0) ----
    stageB(tB, buf ^ 1);
    LOADA(0)
    LOADB(0)
    __builtin_amdgcn_s_barrier();
    MFMAQ(0, 0)
    __builtin_amdgcn_s_barrier();
    // ---- P2: quadrant (0,1) ----
    LOADB(1)
    __builtin_amdgcn_s_barrier();
    MFMAQ(0, 1)
    __builtin_amdgcn_s_barrier();
    // ---- P3: quadrant (1,1) ----
    LOADA(1)
    __builtin_amdgcn_s_barrier();
    MFMAQ(1, 1)
    __builtin_amdgcn_s_barrier();
    // ---- P4: stage A(t+2) -> this buf (A reads ended at P3); counted vmcnt ----
    stageA(tA, buf);
    LOADB(0)
    asm volatile("s_waitcnt vmcnt(%0)" ::"i"(AL) : "memory");
    __builtin_amdgcn_s_barrier();
    MFMAQ(1, 0)
    __builtin_amdgcn_s_barrier();
  }

#pragma unroll
  for (int i = 0; i < MF; i++)
#pragma unroll
    for (int j = 0; j < NF; j++)
#pragma unroll
      for (int rr = 0; rr < 4; rr++)
        C[(size_t)(row0 + wr * (BM / WM) + i * 16 + l4 * 4 + rr) * N +
          (col0 + wc * (BN / WN) + j * 16 + l15)] = acc[i][j][rr];
}

// ---------------- RMSNorm + RoPE + layout ----------------
__global__ void __launch_bounds__(256) qkv_post(const float* __restrict__ QKV,
                                                const float* __restrict__ qw,
                                                const float* __restrict__ kw,
                                                bf16* __restrict__ Qo,
                                                bf16* __restrict__ Ko,
                                                bf16* __restrict__ Vto) {
  const int g = blockIdx.x * 4 + (threadIdx.x >> 6);
  const int lane = threadIdx.x & 63;
  const int hh = g % 24;
  const int bt = g / 24;
  const int b = bt >> 11, t = bt & (T_SEQ - 1);
  int off;
  if (hh < 16) off = hh * 128;
  else if (hh < 20) off = 2048 + (hh - 16) * 128;
  else off = 2560 + (hh - 20) * 128;
  const float2 x = *(const float2*)(QKV + (size_t)bt * 3072 + off + lane * 2);
  if (hh < 20) {
    float ss = x.x * x.x + x.y * x.y;
    ss += __shfl_xor(ss, 1);  ss += __shfl_xor(ss, 2);  ss += __shfl_xor(ss, 4);
    ss += __shfl_xor(ss, 8);  ss += __shfl_xor(ss, 16); ss += __shfl_xor(ss, 32);
    const float rms = rsqrtf(ss * (1.0f / 128.0f) + 1e-5f);
    const float* w = (hh < 16) ? qw : kw;
    const float x0 = x.x * rms * w[lane * 2];
    const float x1 = x.y * rms * w[lane * 2 + 1];
    const float inv = exp2f((float)lane * (-13.287712379549449f / 64.0f));
    const float th = (float)t * inv;
    const float sn = sinf(th), cs = cosf(th);
    const float y0 = x0 * cs - x1 * sn;
    const float y1 = x0 * sn + x1 * cs;
    const bf16 o0 = __float2bfloat16(y0), o1 = __float2bfloat16(y1);
    if (hh < 16) {
      bf16* d = Qo + ((size_t)(b * NHEAD + hh) * T_SEQ + t) * HD + lane * 2;
      d[0] = o0; d[1] = o1;
    } else {
      bf16* d = Ko + ((size_t)(b * NKV + (hh - 16)) * T_SEQ + t) * HD + lane * 2;
      d[0] = o0; d[1] = o1;
    }
  } else {
    bf16* d = Vto + ((size_t)(b * NKV + (hh - 20)) * HD + lane * 2) * T_SEQ + t;
    d[0] = __float2bfloat16(x.x);
    d[T_SEQ] = __float2bfloat16(x.y);
  }
}

// ---------------- GQA causal flash attention, swapped-operand 32x32 MFMA ----------------
__global__ void __launch_bounds__(256, 2) attn_fwd(const bf16* __restrict__ Q,
                                                   const bf16* __restrict__ K,
                                                   const bf16* __restrict__ Vt,
                                                   bf16* __restrict__ Y) {
  __shared__ bf16 smK[128 * 128];
  __shared__ bf16 smV[128 * 128];

  const int bid = blockIdx.x;
  const int p = bid & 255, sdx = bid >> 8;
  const int bh = p & 31;
  const int jh = p >> 5;
  const int jq = sdx ? (15 - jh) : jh;
  const int h = bh & (NHEAD - 1), b = bh >> 4;
  const int bkv = b * NKV + (h >> 2);

  const int tid = threadIdx.x, wid = tid >> 6, lane = tid & 63;
  const int l31 = lane & 31, hi = lane >> 5;
  const int q0w = jq * 128 + wid * 32;

  const bf16* Kb = K + (size_t)bkv * T_SEQ * HD;
  const bf16* Vb = Vt + (size_t)bkv * HD * T_SEQ;

  const bf16* Qrow = Q + ((size_t)bh * T_SEQ + q0w + l31) * HD + hi * 8;
  short8 qf[8];
#pragma unroll
  for (int ds = 0; ds < 8; ds++) qf[ds] = *(const short8*)(Qrow + ds * 16);

  f32x16 o[4];
#pragma unroll
  for (int d = 0; d < 4; d++) o[d] = (f32x16)(0.f);
  float mrun = -INFINITY, lrun = 0.f;

  constexpr float CL = 0.08838834764831845f * 1.44269504088896340736f;
  const int trow = tid >> 4, tslot = tid & 15;

  for (int t = 0; t <= jq; t++) {
    const int k0 = t * 128;
    __syncthreads();
#pragma unroll
    for (int i = 0; i < 8; i++) {
      const int row = i * 16 + trow;
      const int ss = (tslot ^ (row & 15)) * 8;
      gl_lds16(Kb + (size_t)(k0 + row) * HD + ss, (void*)((char*)smK + i * 4096 + wid * 1024));
      gl_lds16(Vb + (size_t)row * T_SEQ + k0 + ss, (void*)((char*)smV + i * 4096 + wid * 1024));
    }
    __syncthreads();

    const bool lastt = (t == jq);
    const int glim = lastt ? wid : 3;

    f32x16 sg[4];
#pragma unroll
    for (int g = 0; g < 4; g++) {
      if (g > glim) continue;
      f32x16 acc = (f32x16)(0.f);
#pragma unroll
      for (int ds = 0; ds < 8; ds++) {
        const int row = g * 32 + l31;
        const short8 kf = *(const short8*)(smK + (size_t)row * 128 +
                                           (((ds << 1) | hi) ^ (row & 15)) * 8);
        acc = __builtin_amdgcn_mfma_f32_32x32x16_bf16(kf, qf[ds], acc, 0, 0, 0);
      }
      sg[g] = acc;
    }
    float tmax = -INFINITY;
#pragma unroll
    for (int g = 0; g < 4; g++) {
      if (g > glim) continue;
      if (lastt && g == wid) {
#pragma unroll
        for (int r = 0; r < 16; r++) {
          const int kr = (r & 3) + 8 * (r >> 2) + (hi << 2);
          if (kr > l31) sg[g][r] = -INFINITY;
        }
      }
#pragma unroll
      for (int r = 0; r < 16; r++) tmax = fmaxf(tmax, sg[g][r]);
    }
    tmax = fmaxf(tmax, __shfl_xor(tmax, 32));
    const float mnew = fmaxf(mrun, tmax);
    const float f = exp2f((mrun - mnew) * CL);
    mrun = mnew;
    lrun *= f;
#pragma unroll
    for (int d = 0; d < 4; d++)
#pragma unroll
      for (int r = 0; r < 16; r++) o[d][r] *= f;

    float lsum = 0.f;
#pragma unroll
    for (int g = 0; g < 4; g++) {
      if (g > glim) continue;
      float pp[16];
      float s0 = 0.f, s1 = 0.f;
#pragma unroll
      for (int r = 0; r < 16; r++) pp[r] = exp2f((sg[g][r] - mnew) * CL);
#pragma unroll
      for (int r = 0; r < 8; r++) { s0 += pp[2 * r]; s1 += pp[2 * r + 1]; }
      lsum += s0 + s1;

      unsigned int w0 = cvtpk_bf16(pp[0], pp[1]),  w2 = cvtpk_bf16(pp[4], pp[5]);
      unsigned int w1 = cvtpk_bf16(pp[2], pp[3]),  w3 = cvtpk_bf16(pp[6], pp[7]);
      unsigned int w4 = cvtpk_bf16(pp[8], pp[9]),  w6 = cvtpk_bf16(pp[12], pp[13]);
      unsigned int w5 = cvtpk_bf16(pp[10], pp[11]), w7 = cvtpk_bf16(pp[14], pp[15]);
      plswap(w0, w2, hi); plswap(w1, w3, hi);
      plswap(w4, w6, hi); plswap(w5, w7, hi);
      union { unsigned int u[4]; short8 s8; } pa0, pa1;
      pa0.u[0] = w0; pa0.u[1] = w1; pa0.u[2] = w2; pa0.u[3] = w3;
      pa1.u[0] = w4; pa1.u[1] = w5; pa1.u[2] = w6; pa1.u[3] = w7;

#pragma unroll
      for (int d = 0; d < 4; d++) {
        const int row = d * 32 + l31;
        const int ks0 = g * 2, ks1 = g * 2 + 1;
        const short8 vf0 = *(const short8*)(smV + (size_t)row * 128 +
                                            (((ks0 << 1) | hi) ^ (row & 15)) * 8);
        const short8 vf1 = *(const short8*)(smV + (size_t)row * 128 +
                                            (((ks1 << 1) | hi) ^ (row & 15)) * 8);
        o[d] = __builtin_amdgcn_mfma_f32_32x32x16_bf16(vf0, pa0.s8, o[d], 0, 0, 0);
        o[d] = __builtin_amdgcn_mfma_f32_32x32x16_bf16(vf1, pa1.s8, o[d], 0, 0, 0);
      }
    }
    lrun += lsum + __shfl_xor(lsum, 32);
  }

  const float inv = 1.0f / lrun;
  bf16* yrow = Y + ((size_t)(b * T_SEQ + q0w + l31)) * CE + h * HD;
#pragma unroll
  for (int d = 0; d < 4; d++) {
#pragma unroll
    for (int rg = 0; rg < 4; rg++) {
      ushort4 u;
      bf16 e0 = __float2bfloat16(o[d][rg * 4 + 0] * inv);
      bf16 e1 = __float2bfloat16(o[d][rg * 4 + 1] * inv);
      bf16 e2 = __float2bfloat16(o[d][rg * 4 + 2] * inv);
      bf16 e3 = __float2bfloat16(o[d][rg * 4 + 3] * inv);
      u.x = *(const unsigned short*)&e0; u.y = *(const unsigned short*)&e1;
      u.z = *(const unsigned short*)&e2; u.w = *(const unsigned short*)&e3;
      *(ushort4*)(yrow + d * 32 + rg * 8 + (hi << 2)) = u;
    }
  }
}

// ---------------- launch ----------------
extern "C" void kernel_launch(void* const* d_in, const int* in_sizes, int n_in,
                              void* d_out, int out_size, void* d_ws, size_t ws_size,
                              hipStream_t stream) {
  const float* x   = (const float*)d_in[0];
  const float* wq  = (const float*)d_in[1];
  const float* wk  = (const float*)d_in[2];
  const float* wv  = (const float*)d_in[3];
  const float* wc  = (const float*)d_in[4];
  const float* qnw = (const float*)d_in[5];
  const float* knw = (const float*)d_in[6];
  float* out = (float*)d_out;

  char* ws = (char*)d_ws;
  bf16*  xb    = (bf16*)(ws);                    // 16 MB
  bf16*  wqkvt = (bf16*)(ws + 16777216);         // 12 MB
  bf16*  wct   = (bf16*)(ws + 29360128);         //  8 MB
  float* qkv   = (float*)(ws + 37748736);        // 48 MB
  bf16*  Qb    = (bf16*)(ws + 88080384);         // 16 MB (B,H,T,D)
  bf16*  Kb    = (bf16*)(ws + 104857600);        //  4 MB (B,KVH,T,D)
  bf16*  Vtb   = (bf16*)(ws + 109051904);        //  4 MB (B,KVH,D,T)
  bf16*  yb    = (bf16*)(ws + 113246208);        // 16 MB

  cvt_bf16<<<8192, 256, 0, stream>>>(x, xb, 2097152);
  transpose_cvt<<<dim3(64, 64), 256, 0, stream>>>(wq, wqkvt, 2048);
  transpose_cvt<<<dim3(16, 64), 256, 0, stream>>>(wk, wqkvt + (size_t)2048 * 2048, 512);
  transpose_cvt<<<dim3(16, 64), 256, 0, stream>>>(wv, wqkvt + (size_t)2560 * 2048, 512);
  transpose_cvt<<<dim3(64, 64), 256, 0, stream>>>(wc, wct, 2048);
  gemm8p<256, 256, 2, 4><<<192, 512, 0, stream>>>(xb, wqkvt, qkv, 4096, 3072, 2048);
  qkv_post<<<24576, 256, 0, stream>>>(qkv, qnw, knw, Qb, Kb, Vtb);
  attn_fwd<<<512, 256, 0, stream>>>(Qb, Kb, Vtb, yb);
  gemm8p<256, 128, 4, 2><<<256, 512, 0, stream>>>(yb, wct, out, 4096, 2048, 2048);
}